// Round 1
// baseline (498.742 us; speedup 1.0000x reference)
//
#include <hip/hip_runtime.h>
#include <math.h>

#define HID   1024
#define OUTD  8192
#define NSUBJ 8
#define BATCH 64
#define TLEN  512

// ws layout (float offsets)
#define OFF_PP    0u          // pool partials: 8*64*1024
#define OFF_H0    524288u     // 64*1024
#define OFF_P1    589824u     // gemm1 partials: 8*64*1024
#define OFF_G     1114112u    // 64*1024
#define OFF_P2    1179648u    // gemm2 partials: 8*64*1024
#define OFF_H     1703936u    // 64*1024
#define OFF_MUP   1769472u    // mu partials: 8*64*8192
#define OFF_LVP   5963776u    // lv partials: 8*64*8192
#define OFF_INTS  10158080u   // counts[8] + lists[8*64] as int

// ---------------- grouping: one thread builds per-subject sample lists ----------------
__global__ void k_group(const int* __restrict__ sid, int* __restrict__ counts,
                        int* __restrict__ lists) {
    if (threadIdx.x == 0) {
        int c[NSUBJ];
        for (int s = 0; s < NSUBJ; ++s) c[s] = 0;
        for (int b = 0; b < BATCH; ++b) {
            int s = sid[b];
            lists[s * BATCH + c[s]] = b;
            c[s]++;
        }
        for (int s = 0; s < NSUBJ; ++s) counts[s] = c[s];
    }
}

// ---------------- mean pool, stage 1: partial sums over 64-t chunks ----------------
__global__ __launch_bounds__(256) void k_pool(const float* __restrict__ ctx,
                                              float* __restrict__ pp) {
    int b  = blockIdx.x;   // 64
    int tc = blockIdx.y;   // 8
    int hid = threadIdx.x * 4;
    const float* base = ctx + ((size_t)b * TLEN + (size_t)tc * 64) * HID + hid;
    float4 acc = make_float4(0.f, 0.f, 0.f, 0.f);
    for (int t = 0; t < 64; ++t) {
        float4 v = *(const float4*)(base + (size_t)t * HID);
        acc.x += v.x; acc.y += v.y; acc.z += v.z; acc.w += v.w;
    }
    *(float4*)(pp + ((size_t)tc * BATCH + b) * HID + hid) = acc;
}

// ---------------- mean pool, stage 2: reduce 8 partials, divide ----------------
__global__ __launch_bounds__(256) void k_poolred(const float* __restrict__ pp,
                                                 float* __restrict__ h0) {
    int i = blockIdx.x * 256 + threadIdx.x;  // over 65536
    float s = 0.f;
#pragma unroll
    for (int tc = 0; tc < 8; ++tc) s += pp[tc * 65536 + i];
    h0[i] = s * (1.0f / 512.0f);
}

// ---------------- MLP GEMM partial: p[kc][b][j] = sum_{k in chunk} x[b][k]*w[k][j] ----
__global__ __launch_bounds__(256) void k_gemm_mlp(const float* __restrict__ x,
                                                  const float* __restrict__ w,
                                                  float* __restrict__ p) {
    int j  = blockIdx.x * 256 + threadIdx.x;  // 4 ochunks
    int k0 = blockIdx.y * 128;                // 8 kchunks
    int b0 = blockIdx.z * 32;                 // 2 bgroups
    float acc[32];
#pragma unroll
    for (int i = 0; i < 32; ++i) acc[i] = 0.f;
    for (int k = k0; k < k0 + 128; ++k) {
        float wv = w[k * HID + j];
#pragma unroll
        for (int i = 0; i < 32; ++i)
            acc[i] = fmaf(x[(b0 + i) * HID + k], wv, acc[i]);
    }
    float* dst = p + (size_t)blockIdx.y * BATCH * HID;
#pragma unroll
    for (int i = 0; i < 32; ++i) dst[(b0 + i) * HID + j] = acc[i];
}

// ---------------- reduce partials + bias + exact GELU ----------------
__global__ __launch_bounds__(256) void k_red_gelu(const float* __restrict__ p,
                                                  const float* __restrict__ bias,
                                                  float* __restrict__ out) {
    int i = blockIdx.x * 256 + threadIdx.x;
    int j = i & (HID - 1);
    float s = 0.f;
#pragma unroll
    for (int kc = 0; kc < 8; ++kc) s += p[kc * 65536 + i];
    s += bias[j];
    out[i] = 0.5f * s * (1.0f + erff(s * 0.70710678118654752f));
}

// ---------------- reduce partials + bias ----------------
__global__ __launch_bounds__(256) void k_red_bias(const float* __restrict__ p,
                                                  const float* __restrict__ bias,
                                                  float* __restrict__ out) {
    int i = blockIdx.x * 256 + threadIdx.x;
    int j = i & (HID - 1);
    float s = 0.f;
#pragma unroll
    for (int kc = 0; kc < 8; ++kc) s += p[kc * 65536 + i];
    out[i] = s + bias[j];
}

// ---------------- mu partial: grouped by subject so each weight is read once --------
__global__ __launch_bounds__(256) void k_mu(const float* __restrict__ hmat,
                                            const float* __restrict__ subj_w,
                                            const int* __restrict__ counts,
                                            const int* __restrict__ lists,
                                            float* __restrict__ mup) {
    int o  = blockIdx.x * 512 + threadIdx.x * 2;  // 16 ochunks, float2
    int k0 = blockIdx.y * 128;                    // 8 kchunks
    int s  = blockIdx.z;                          // 8 subjects
    int ns = counts[s];
    const float* wbase = subj_w + (size_t)s * HID * OUTD;
    for (int base = 0; base < ns; base += 16) {
        int n = ns - base; if (n > 16) n = 16;
        int bi[16];
#pragma unroll
        for (int i = 0; i < 16; ++i)
            bi[i] = lists[s * BATCH + base + (i < n ? i : 0)];
        float2 acc[16];
#pragma unroll
        for (int i = 0; i < 16; ++i) acc[i] = make_float2(0.f, 0.f);
        for (int k = k0; k < k0 + 128; ++k) {
            float2 wv = *(const float2*)(wbase + (size_t)k * OUTD + o);
#pragma unroll
            for (int i = 0; i < 16; ++i) {
                float hv = hmat[bi[i] * HID + k];
                acc[i].x = fmaf(hv, wv.x, acc[i].x);
                acc[i].y = fmaf(hv, wv.y, acc[i].y);
            }
        }
#pragma unroll
        for (int i = 0; i < 16; ++i) {
            if (i < n) {
                float* dst = mup + ((size_t)blockIdx.y * BATCH + bi[i]) * OUTD + o;
                dst[0] = acc[i].x; dst[1] = acc[i].y;
            }
        }
    }
}

// ---------------- log_var partial: all-b shared weight read (2 bgroups) -------------
__global__ __launch_bounds__(256) void k_lv(const float* __restrict__ hmat,
                                            const float* __restrict__ lv_w,
                                            float* __restrict__ lvp) {
    int o  = blockIdx.x * 512 + threadIdx.x * 2;  // 16 ochunks
    int k0 = blockIdx.y * 128;                    // 8 kchunks
    int b0 = blockIdx.z * 32;                     // 2 bgroups
    float2 acc[32];
#pragma unroll
    for (int i = 0; i < 32; ++i) acc[i] = make_float2(0.f, 0.f);
    for (int k = k0; k < k0 + 128; ++k) {
        float2 wv = *(const float2*)(lv_w + (size_t)k * OUTD + o);
#pragma unroll
        for (int i = 0; i < 32; ++i) {
            float hv = hmat[(b0 + i) * HID + k];
            acc[i].x = fmaf(hv, wv.x, acc[i].x);
            acc[i].y = fmaf(hv, wv.y, acc[i].y);
        }
    }
#pragma unroll
    for (int i = 0; i < 32; ++i) {
        float* dst = lvp + ((size_t)blockIdx.y * BATCH + b0 + i) * OUTD + o;
        dst[0] = acc[i].x; dst[1] = acc[i].y;
    }
}

// ---------------- combine: biases, clip, sample; write x0|mu|log_var ----------------
__global__ __launch_bounds__(256) void k_combine(const float* __restrict__ mup,
                                                 const float* __restrict__ lvp,
                                                 const float* __restrict__ eps,
                                                 const float* __restrict__ subj_b,
                                                 const float* __restrict__ lv_b,
                                                 const int* __restrict__ sid,
                                                 float* __restrict__ out) {
    int idx = blockIdx.x * 256 + threadIdx.x;  // over 524288
    int b = idx >> 13;
    int o = idx & (OUTD - 1);
    float m = 0.f, l = 0.f;
#pragma unroll
    for (int kc = 0; kc < 8; ++kc) {
        m += mup[kc * 524288 + idx];
        l += lvp[kc * 524288 + idx];
    }
    m += subj_b[sid[b] * OUTD + o];
    l += lv_b[o];
    l = fminf(fmaxf(l, -10.0f), 2.0f);
    float x0 = m + eps[idx] * __expf(0.5f * l) ;
    out[idx] = x0;
    out[524288 + idx] = m;
    out[1048576 + idx] = l;
}

extern "C" void kernel_launch(void* const* d_in, const int* in_sizes, int n_in,
                              void* d_out, int out_size, void* d_ws, size_t ws_size,
                              hipStream_t stream) {
    const float* ctx    = (const float*)d_in[0];
    const int*   sid    = (const int*)  d_in[1];
    const float* eps    = (const float*)d_in[2];
    const float* w1     = (const float*)d_in[3];
    const float* b1     = (const float*)d_in[4];
    const float* w2     = (const float*)d_in[5];
    const float* b2     = (const float*)d_in[6];
    const float* subj_w = (const float*)d_in[7];
    const float* subj_b = (const float*)d_in[8];
    const float* lv_w   = (const float*)d_in[9];
    const float* lv_b   = (const float*)d_in[10];
    float* out = (float*)d_out;

    float* ws   = (float*)d_ws;
    float* pp   = ws + OFF_PP;
    float* h0   = ws + OFF_H0;
    float* p1   = ws + OFF_P1;
    float* g    = ws + OFF_G;
    float* p2   = ws + OFF_P2;
    float* hbuf = ws + OFF_H;
    float* mup  = ws + OFF_MUP;
    float* lvp  = ws + OFF_LVP;
    int* counts = (int*)(ws + OFF_INTS);
    int* lists  = counts + NSUBJ;

    k_group<<<1, 64, 0, stream>>>(sid, counts, lists);
    k_pool<<<dim3(BATCH, 8), 256, 0, stream>>>(ctx, pp);
    k_poolred<<<256, 256, 0, stream>>>(pp, h0);
    k_gemm_mlp<<<dim3(4, 8, 2), 256, 0, stream>>>(h0, w1, p1);
    k_red_gelu<<<256, 256, 0, stream>>>(p1, b1, g);
    k_gemm_mlp<<<dim3(4, 8, 2), 256, 0, stream>>>(g, w2, p2);
    k_red_bias<<<256, 256, 0, stream>>>(p2, b2, hbuf);
    k_mu<<<dim3(16, 8, NSUBJ), 256, 0, stream>>>(hbuf, subj_w, counts, lists, mup);
    k_lv<<<dim3(16, 8, 2), 256, 0, stream>>>(hbuf, lv_w, lvp);
    k_combine<<<2048, 256, 0, stream>>>(mup, lvp, eps, subj_b, lv_b, sid, out);
}

// Round 2
// 287.967 us; speedup vs baseline: 1.7319x; 1.7319x over previous
//
#include <hip/hip_runtime.h>
#include <math.h>

#define HID   1024
#define OUTD  8192
#define NSUBJ 8
#define BATCH 64
#define TLEN  512

// ws layout (float offsets)
#define OFF_PP    0u           // pool partials: 16*64*1024
#define OFF_H0    1048576u     // 64*1024
#define OFF_P1    1114112u     // gemm1 partials: 8*64*1024
#define OFF_G     1638400u     // 64*1024
#define OFF_P2    1703936u     // gemm2 partials: 8*64*1024
#define OFF_H     2228224u     // 64*1024
#define OFF_MUP   2293760u     // mu partials: 8*64*8192
#define OFF_LVP   6488064u     // lv partials: 8*64*8192
#define OFF_INTS  10682368u    // counts[8] + lists[8*64] as int

// ---------------- grouping: one wave, ballot-based, no serial chain ----------------
__global__ void k_group(const int* __restrict__ sid, int* __restrict__ counts,
                        int* __restrict__ lists) {
    int lane = threadIdx.x;            // 64 threads = 1 wave
    int my = sid[lane];
    unsigned long long before = (lane == 63) ? 0xFFFFFFFFFFFFFFFFull >> 1
                                             : ((1ull << lane) - 1ull);
#pragma unroll
    for (int s = 0; s < NSUBJ; ++s) {
        unsigned long long m = __ballot(my == s);
        if (my == s) {
            int pos = __popcll(m & before);
            lists[s * BATCH + pos] = lane;
        }
        if (lane == 0) counts[s] = __popcll(m);
    }
}

// ---------------- mean pool, stage 1: partial sums over 32-t chunks ----------------
__global__ __launch_bounds__(256) void k_pool(const float* __restrict__ ctx,
                                              float* __restrict__ pp) {
    int b  = blockIdx.x;   // 64
    int tc = blockIdx.y;   // 16
    int hid = threadIdx.x * 4;
    const float* base = ctx + ((size_t)b * TLEN + (size_t)tc * 32) * HID + hid;
    float4 acc = make_float4(0.f, 0.f, 0.f, 0.f);
#pragma unroll 8
    for (int t = 0; t < 32; ++t) {
        float4 v = *(const float4*)(base + (size_t)t * HID);
        acc.x += v.x; acc.y += v.y; acc.z += v.z; acc.w += v.w;
    }
    *(float4*)(pp + ((size_t)tc * BATCH + b) * HID + hid) = acc;
}

// ---------------- mean pool, stage 2: reduce 16 partials, divide ----------------
__global__ __launch_bounds__(256) void k_poolred(const float* __restrict__ pp,
                                                 float* __restrict__ h0) {
    int i = blockIdx.x * 256 + threadIdx.x;  // over 65536
    float s = 0.f;
#pragma unroll
    for (int tc = 0; tc < 16; ++tc) s += pp[tc * 65536 + i];
    h0[i] = s * (1.0f / 512.0f);
}

// ---------------- MLP GEMM partial, k-tiled float2 x loads ----------------
__global__ __launch_bounds__(256) void k_gemm_mlp(const float* __restrict__ x,
                                                  const float* __restrict__ w,
                                                  float* __restrict__ p) {
    int j  = blockIdx.x * 256 + threadIdx.x;  // 4 ochunks
    int k0 = blockIdx.y * 128;                // 8 kchunks
    int b0 = blockIdx.z * 32;                 // 2 bgroups
    float acc[32];
#pragma unroll
    for (int i = 0; i < 32; ++i) acc[i] = 0.f;
    for (int k = k0; k < k0 + 128; k += 2) {
        float2 xv[32];
#pragma unroll
        for (int i = 0; i < 32; ++i)
            xv[i] = *(const float2*)(x + (b0 + i) * HID + k);
        float w0 = w[k * HID + j];
        float w1 = w[(k + 1) * HID + j];
#pragma unroll
        for (int i = 0; i < 32; ++i)
            acc[i] = fmaf(xv[i].y, w1, fmaf(xv[i].x, w0, acc[i]));
    }
    float* dst = p + (size_t)blockIdx.y * BATCH * HID;
#pragma unroll
    for (int i = 0; i < 32; ++i) dst[(b0 + i) * HID + j] = acc[i];
}

// ---------------- reduce partials + bias + exact GELU ----------------
__global__ __launch_bounds__(256) void k_red_gelu(const float* __restrict__ p,
                                                  const float* __restrict__ bias,
                                                  float* __restrict__ out) {
    int i = blockIdx.x * 256 + threadIdx.x;
    int j = i & (HID - 1);
    float s = 0.f;
#pragma unroll
    for (int kc = 0; kc < 8; ++kc) s += p[kc * 65536 + i];
    s += bias[j];
    out[i] = 0.5f * s * (1.0f + erff(s * 0.70710678118654752f));
}

// ---------------- reduce partials + bias ----------------
__global__ __launch_bounds__(256) void k_red_bias(const float* __restrict__ p,
                                                  const float* __restrict__ bias,
                                                  float* __restrict__ out) {
    int i = blockIdx.x * 256 + threadIdx.x;
    int j = i & (HID - 1);
    float s = 0.f;
#pragma unroll
    for (int kc = 0; kc < 8; ++kc) s += p[kc * 65536 + i];
    out[i] = s + bias[j];
}

// ------- mu partial: float4 weights, k-tile 4, float4 h loads, 16-sample tile ------
__global__ __launch_bounds__(256) void k_mu(const float* __restrict__ hmat,
                                            const float* __restrict__ subj_w,
                                            const int* __restrict__ counts,
                                            const int* __restrict__ lists,
                                            float* __restrict__ mup) {
    int o  = blockIdx.x * 1024 + threadIdx.x * 4;  // 8 ochunks, float4
    int k0 = blockIdx.y * 128;                     // 8 kchunks
    int s  = blockIdx.z;                           // 8 subjects
    int ns = counts[s];
    const float* wbase = subj_w + (size_t)s * HID * OUTD;
    for (int base = 0; base < ns; base += 16) {
        int n = ns - base; if (n > 16) n = 16;
        int bo[16];
#pragma unroll
        for (int i = 0; i < 16; ++i)
            bo[i] = lists[s * BATCH + base + (i < n ? i : 0)];
        float4 acc[16];
#pragma unroll
        for (int i = 0; i < 16; ++i) acc[i] = make_float4(0.f, 0.f, 0.f, 0.f);
        for (int k = k0; k < k0 + 128; k += 4) {
            float4 hv[16];
#pragma unroll
            for (int i = 0; i < 16; ++i)
                hv[i] = *(const float4*)(hmat + bo[i] * HID + k);
#pragma unroll
            for (int kk = 0; kk < 4; ++kk) {
                float4 wv = *(const float4*)(wbase + (size_t)(k + kk) * OUTD + o);
#pragma unroll
                for (int i = 0; i < 16; ++i) {
                    float h = (kk == 0) ? hv[i].x : (kk == 1) ? hv[i].y
                            : (kk == 2) ? hv[i].z : hv[i].w;
                    acc[i].x = fmaf(h, wv.x, acc[i].x);
                    acc[i].y = fmaf(h, wv.y, acc[i].y);
                    acc[i].z = fmaf(h, wv.z, acc[i].z);
                    acc[i].w = fmaf(h, wv.w, acc[i].w);
                }
            }
        }
#pragma unroll
        for (int i = 0; i < 16; ++i) {
            if (i < n) {
                *(float4*)(mup + ((size_t)blockIdx.y * BATCH + bo[i]) * OUTD + o) = acc[i];
            }
        }
    }
}

// ---------------- log_var partial: all-b shared weight read (2 bgroups) -------------
__global__ __launch_bounds__(256) void k_lv(const float* __restrict__ hmat,
                                            const float* __restrict__ lv_w,
                                            float* __restrict__ lvp) {
    int o  = blockIdx.x * 512 + threadIdx.x * 2;  // 16 ochunks
    int k0 = blockIdx.y * 128;                    // 8 kchunks
    int b0 = blockIdx.z * 32;                     // 2 bgroups
    float2 acc[32];
#pragma unroll
    for (int i = 0; i < 32; ++i) acc[i] = make_float2(0.f, 0.f);
    for (int k = k0; k < k0 + 128; k += 2) {
        float2 hv[32];
#pragma unroll
        for (int i = 0; i < 32; ++i)
            hv[i] = *(const float2*)(hmat + (b0 + i) * HID + k);
        float2 wv0 = *(const float2*)(lv_w + (size_t)k * OUTD + o);
        float2 wv1 = *(const float2*)(lv_w + (size_t)(k + 1) * OUTD + o);
#pragma unroll
        for (int i = 0; i < 32; ++i) {
            acc[i].x = fmaf(hv[i].x, wv0.x, acc[i].x);
            acc[i].y = fmaf(hv[i].x, wv0.y, acc[i].y);
            acc[i].x = fmaf(hv[i].y, wv1.x, acc[i].x);
            acc[i].y = fmaf(hv[i].y, wv1.y, acc[i].y);
        }
    }
#pragma unroll
    for (int i = 0; i < 32; ++i) {
        float* dst = lvp + ((size_t)blockIdx.y * BATCH + b0 + i) * OUTD + o;
        dst[0] = acc[i].x; dst[1] = acc[i].y;
    }
}

// ---------------- combine: biases, clip, sample; write x0|mu|log_var ----------------
__global__ __launch_bounds__(256) void k_combine(const float* __restrict__ mup,
                                                 const float* __restrict__ lvp,
                                                 const float* __restrict__ eps,
                                                 const float* __restrict__ subj_b,
                                                 const float* __restrict__ lv_b,
                                                 const int* __restrict__ sid,
                                                 float* __restrict__ out) {
    int idx = (blockIdx.x * 256 + threadIdx.x) * 4;  // over 524288, float4
    int b = idx >> 13;
    int o = idx & (OUTD - 1);
    float4 m = make_float4(0.f, 0.f, 0.f, 0.f);
    float4 l = make_float4(0.f, 0.f, 0.f, 0.f);
#pragma unroll
    for (int kc = 0; kc < 8; ++kc) {
        float4 t = *(const float4*)(mup + kc * 524288 + idx);
        m.x += t.x; m.y += t.y; m.z += t.z; m.w += t.w;
        float4 u = *(const float4*)(lvp + kc * 524288 + idx);
        l.x += u.x; l.y += u.y; l.z += u.z; l.w += u.w;
    }
    int s = sid[b];
    float4 sb = *(const float4*)(subj_b + s * OUTD + o);
    float4 lb = *(const float4*)(lv_b + o);
    m.x += sb.x; m.y += sb.y; m.z += sb.z; m.w += sb.w;
    l.x = fminf(fmaxf(l.x + lb.x, -10.f), 2.f);
    l.y = fminf(fmaxf(l.y + lb.y, -10.f), 2.f);
    l.z = fminf(fmaxf(l.z + lb.z, -10.f), 2.f);
    l.w = fminf(fmaxf(l.w + lb.w, -10.f), 2.f);
    float4 e = *(const float4*)(eps + idx);
    float4 x0;
    x0.x = m.x + e.x * __expf(0.5f * l.x);
    x0.y = m.y + e.y * __expf(0.5f * l.y);
    x0.z = m.z + e.z * __expf(0.5f * l.z);
    x0.w = m.w + e.w * __expf(0.5f * l.w);
    *(float4*)(out + idx) = x0;
    *(float4*)(out + 524288 + idx) = m;
    *(float4*)(out + 1048576 + idx) = l;
}

extern "C" void kernel_launch(void* const* d_in, const int* in_sizes, int n_in,
                              void* d_out, int out_size, void* d_ws, size_t ws_size,
                              hipStream_t stream) {
    const float* ctx    = (const float*)d_in[0];
    const int*   sid    = (const int*)  d_in[1];
    const float* eps    = (const float*)d_in[2];
    const float* w1     = (const float*)d_in[3];
    const float* b1     = (const float*)d_in[4];
    const float* w2     = (const float*)d_in[5];
    const float* b2     = (const float*)d_in[6];
    const float* subj_w = (const float*)d_in[7];
    const float* subj_b = (const float*)d_in[8];
    const float* lv_w   = (const float*)d_in[9];
    const float* lv_b   = (const float*)d_in[10];
    float* out = (float*)d_out;

    float* ws   = (float*)d_ws;
    float* pp   = ws + OFF_PP;
    float* h0   = ws + OFF_H0;
    float* p1   = ws + OFF_P1;
    float* g    = ws + OFF_G;
    float* p2   = ws + OFF_P2;
    float* hbuf = ws + OFF_H;
    float* mup  = ws + OFF_MUP;
    float* lvp  = ws + OFF_LVP;
    int* counts = (int*)(ws + OFF_INTS);
    int* lists  = counts + NSUBJ;

    k_group<<<1, 64, 0, stream>>>(sid, counts, lists);
    k_pool<<<dim3(BATCH, 16), 256, 0, stream>>>(ctx, pp);
    k_poolred<<<256, 256, 0, stream>>>(pp, h0);
    k_gemm_mlp<<<dim3(4, 8, 2), 256, 0, stream>>>(h0, w1, p1);
    k_red_gelu<<<256, 256, 0, stream>>>(p1, b1, g);
    k_gemm_mlp<<<dim3(4, 8, 2), 256, 0, stream>>>(g, w2, p2);
    k_red_bias<<<256, 256, 0, stream>>>(p2, b2, hbuf);
    k_mu<<<dim3(8, 8, NSUBJ), 256, 0, stream>>>(hbuf, subj_w, counts, lists, mup);
    k_lv<<<dim3(16, 8, 2), 256, 0, stream>>>(hbuf, lv_w, lvp);
    k_combine<<<512, 256, 0, stream>>>(mup, lvp, eps, subj_b, lv_b, sid, out);
}

// Round 3
// 226.825 us; speedup vs baseline: 2.1988x; 1.2696x over previous
//
#include <hip/hip_runtime.h>
#include <math.h>

#define HID   1024
#define OUTD  8192
#define NSUBJ 8
#define BATCH 64
#define TLEN  512

// ws layout (float offsets)
#define OFF_PP    0u           // pool partials: 32*64*1024
#define OFF_H0    2097152u     // 64*1024
#define OFF_P1    2162688u     // gemm1 partials: 32*64*1024
#define OFF_G     4259840u     // 64*1024
#define OFF_P2    4325376u     // gemm2 partials: 32*64*1024
#define OFF_H     6422528u     // 64*1024
#define OFF_MUP   6488064u     // mu partials: 8*64*8192
#define OFF_LVP   10682368u    // lv partials: 8*64*8192

// ---------------- mean pool, stage 1: partial sums over 16-t chunks ----------------
__global__ __launch_bounds__(256) void k_pool(const float* __restrict__ ctx,
                                              float* __restrict__ pp) {
    int b  = blockIdx.x;   // 64
    int tc = blockIdx.y;   // 32
    int hid = threadIdx.x * 4;
    const float* base = ctx + ((size_t)b * TLEN + (size_t)tc * 16) * HID + hid;
    float4 acc = make_float4(0.f, 0.f, 0.f, 0.f);
#pragma unroll
    for (int t = 0; t < 16; ++t) {
        float4 v = *(const float4*)(base + (size_t)t * HID);
        acc.x += v.x; acc.y += v.y; acc.z += v.z; acc.w += v.w;
    }
    *(float4*)(pp + ((size_t)tc * BATCH + b) * HID + hid) = acc;
}

// ---------------- mean pool, stage 2: reduce 32 partials, divide ----------------
__global__ __launch_bounds__(256) void k_poolred(const float* __restrict__ pp,
                                                 float* __restrict__ h0) {
    int i = (blockIdx.x * 256 + threadIdx.x) * 4;  // over 65536 -> 64 blocks
    float4 s = make_float4(0.f, 0.f, 0.f, 0.f);
#pragma unroll
    for (int tc = 0; tc < 32; ++tc) {
        float4 v = *(const float4*)(pp + (size_t)tc * 65536 + i);
        s.x += v.x; s.y += v.y; s.z += v.z; s.w += v.w;
    }
    s.x *= (1.f/512.f); s.y *= (1.f/512.f); s.z *= (1.f/512.f); s.w *= (1.f/512.f);
    *(float4*)(h0 + i) = s;
}

// ---------------- MLP GEMM partial: k-chunk 32, 256 blocks ----------------
__global__ __launch_bounds__(256) void k_gemm_mlp(const float* __restrict__ x,
                                                  const float* __restrict__ w,
                                                  float* __restrict__ p) {
    int j  = blockIdx.x * 256 + threadIdx.x;  // 4 ochunks
    int k0 = blockIdx.y * 32;                 // 32 kchunks
    int b0 = blockIdx.z * 32;                 // 2 bgroups
    float acc[32];
#pragma unroll
    for (int i = 0; i < 32; ++i) acc[i] = 0.f;
    for (int k = k0; k < k0 + 32; k += 2) {
        float2 xv[32];
#pragma unroll
        for (int i = 0; i < 32; ++i)
            xv[i] = *(const float2*)(x + (b0 + i) * HID + k);
        float w0 = w[k * HID + j];
        float w1 = w[(k + 1) * HID + j];
#pragma unroll
        for (int i = 0; i < 32; ++i)
            acc[i] = fmaf(xv[i].y, w1, fmaf(xv[i].x, w0, acc[i]));
    }
    float* dst = p + (size_t)blockIdx.y * BATCH * HID;
#pragma unroll
    for (int i = 0; i < 32; ++i) dst[(b0 + i) * HID + j] = acc[i];
}

// ---------------- reduce 32 partials + bias + exact GELU, float4 ----------------
__global__ __launch_bounds__(256) void k_red_gelu(const float* __restrict__ p,
                                                  const float* __restrict__ bias,
                                                  float* __restrict__ out) {
    int i = (blockIdx.x * 256 + threadIdx.x) * 4;  // 64 blocks
    int j = i & (HID - 1);
    float4 s = make_float4(0.f, 0.f, 0.f, 0.f);
#pragma unroll
    for (int kc = 0; kc < 32; ++kc) {
        float4 v = *(const float4*)(p + (size_t)kc * 65536 + i);
        s.x += v.x; s.y += v.y; s.z += v.z; s.w += v.w;
    }
    float4 bb = *(const float4*)(bias + j);
    s.x += bb.x; s.y += bb.y; s.z += bb.z; s.w += bb.w;
    const float r = 0.70710678118654752f;
    s.x = 0.5f * s.x * (1.0f + erff(s.x * r));
    s.y = 0.5f * s.y * (1.0f + erff(s.y * r));
    s.z = 0.5f * s.z * (1.0f + erff(s.z * r));
    s.w = 0.5f * s.w * (1.0f + erff(s.w * r));
    *(float4*)(out + i) = s;
}

// ---------------- reduce 32 partials + bias, float4 ----------------
__global__ __launch_bounds__(256) void k_red_bias(const float* __restrict__ p,
                                                  const float* __restrict__ bias,
                                                  float* __restrict__ out) {
    int i = (blockIdx.x * 256 + threadIdx.x) * 4;  // 64 blocks
    int j = i & (HID - 1);
    float4 s = make_float4(0.f, 0.f, 0.f, 0.f);
#pragma unroll
    for (int kc = 0; kc < 32; ++kc) {
        float4 v = *(const float4*)(p + (size_t)kc * 65536 + i);
        s.x += v.x; s.y += v.y; s.z += v.z; s.w += v.w;
    }
    float4 bb = *(const float4*)(bias + j);
    s.x += bb.x; s.y += bb.y; s.z += bb.z; s.w += bb.w;
    *(float4*)(out + i) = s;
}

// ------- mu partial: 8-sample tile (matches ~8 samples/subject), inline grouping ----
__global__ __launch_bounds__(256) void k_mu(const float* __restrict__ hmat,
                                            const float* __restrict__ subj_w,
                                            const int* __restrict__ sid,
                                            float* __restrict__ mup) {
    int o  = blockIdx.x * 1024 + threadIdx.x * 4;  // 8 ochunks, float4
    int k0 = blockIdx.y * 128;                     // 8 kchunks
    int s  = blockIdx.z;                           // 8 subjects
    // in-wave grouping: lane b checks sid[b]; mask is wave-uniform
    int lane = threadIdx.x & 63;
    int mysid = sid[lane];
    unsigned long long m = __ballot(mysid == s);
    int ns = __popcll(m);
    if (ns == 0) return;
    const float* wbase = subj_w + (size_t)s * HID * OUTD;
    unsigned long long mm = m;
    for (int base = 0; base < ns; base += 8) {
        int n = ns - base; if (n > 8) n = 8;
        int bo[8];
#pragma unroll
        for (int i = 0; i < 8; ++i) {
            bo[i] = (mm != 0ull) ? (int)__builtin_ctzll(mm) : 0;
            if (mm != 0ull) mm &= (mm - 1ull);
        }
        float4 acc[8];
#pragma unroll
        for (int i = 0; i < 8; ++i) acc[i] = make_float4(0.f, 0.f, 0.f, 0.f);
        for (int k = k0; k < k0 + 128; k += 4) {
            float4 hv[8];
#pragma unroll
            for (int i = 0; i < 8; ++i)
                hv[i] = *(const float4*)(hmat + bo[i] * HID + k);
#pragma unroll
            for (int kk = 0; kk < 4; ++kk) {
                float4 wv = *(const float4*)(wbase + (size_t)(k + kk) * OUTD + o);
#pragma unroll
                for (int i = 0; i < 8; ++i) {
                    float h = (kk == 0) ? hv[i].x : (kk == 1) ? hv[i].y
                            : (kk == 2) ? hv[i].z : hv[i].w;
                    acc[i].x = fmaf(h, wv.x, acc[i].x);
                    acc[i].y = fmaf(h, wv.y, acc[i].y);
                    acc[i].z = fmaf(h, wv.z, acc[i].z);
                    acc[i].w = fmaf(h, wv.w, acc[i].w);
                }
            }
        }
#pragma unroll
        for (int i = 0; i < 8; ++i) {
            if (i < n) {
                *(float4*)(mup + ((size_t)blockIdx.y * BATCH + bo[i]) * OUTD + o) = acc[i];
            }
        }
    }
}

// ---------------- log_var partial: all-b shared weight read (2 bgroups) -------------
__global__ __launch_bounds__(256) void k_lv(const float* __restrict__ hmat,
                                            const float* __restrict__ lv_w,
                                            float* __restrict__ lvp) {
    int o  = blockIdx.x * 512 + threadIdx.x * 2;  // 16 ochunks
    int k0 = blockIdx.y * 128;                    // 8 kchunks
    int b0 = blockIdx.z * 32;                     // 2 bgroups
    float2 acc[32];
#pragma unroll
    for (int i = 0; i < 32; ++i) acc[i] = make_float2(0.f, 0.f);
    for (int k = k0; k < k0 + 128; k += 2) {
        float2 hv[32];
#pragma unroll
        for (int i = 0; i < 32; ++i)
            hv[i] = *(const float2*)(hmat + (b0 + i) * HID + k);
        float2 wv0 = *(const float2*)(lv_w + (size_t)k * OUTD + o);
        float2 wv1 = *(const float2*)(lv_w + (size_t)(k + 1) * OUTD + o);
#pragma unroll
        for (int i = 0; i < 32; ++i) {
            acc[i].x = fmaf(hv[i].x, wv0.x, acc[i].x);
            acc[i].y = fmaf(hv[i].x, wv0.y, acc[i].y);
            acc[i].x = fmaf(hv[i].y, wv1.x, acc[i].x);
            acc[i].y = fmaf(hv[i].y, wv1.y, acc[i].y);
        }
    }
#pragma unroll
    for (int i = 0; i < 32; ++i) {
        float* dst = lvp + ((size_t)blockIdx.y * BATCH + b0 + i) * OUTD + o;
        dst[0] = acc[i].x; dst[1] = acc[i].y;
    }
}

// ---------------- combine: biases, clip, sample; write x0|mu|log_var ----------------
__global__ __launch_bounds__(256) void k_combine(const float* __restrict__ mup,
                                                 const float* __restrict__ lvp,
                                                 const float* __restrict__ eps,
                                                 const float* __restrict__ subj_b,
                                                 const float* __restrict__ lv_b,
                                                 const int* __restrict__ sid,
                                                 float* __restrict__ out) {
    int idx = (blockIdx.x * 256 + threadIdx.x) * 4;  // over 524288, float4
    int b = idx >> 13;
    int o = idx & (OUTD - 1);
    float4 m = make_float4(0.f, 0.f, 0.f, 0.f);
    float4 l = make_float4(0.f, 0.f, 0.f, 0.f);
#pragma unroll
    for (int kc = 0; kc < 8; ++kc) {
        float4 t = *(const float4*)(mup + (size_t)kc * 524288 + idx);
        m.x += t.x; m.y += t.y; m.z += t.z; m.w += t.w;
        float4 u = *(const float4*)(lvp + (size_t)kc * 524288 + idx);
        l.x += u.x; l.y += u.y; l.z += u.z; l.w += u.w;
    }
    int s = sid[b];
    float4 sb = *(const float4*)(subj_b + s * OUTD + o);
    float4 lb = *(const float4*)(lv_b + o);
    m.x += sb.x; m.y += sb.y; m.z += sb.z; m.w += sb.w;
    l.x = fminf(fmaxf(l.x + lb.x, -10.f), 2.f);
    l.y = fminf(fmaxf(l.y + lb.y, -10.f), 2.f);
    l.z = fminf(fmaxf(l.z + lb.z, -10.f), 2.f);
    l.w = fminf(fmaxf(l.w + lb.w, -10.f), 2.f);
    float4 e = *(const float4*)(eps + idx);
    float4 x0;
    x0.x = m.x + e.x * __expf(0.5f * l.x);
    x0.y = m.y + e.y * __expf(0.5f * l.y);
    x0.z = m.z + e.z * __expf(0.5f * l.z);
    x0.w = m.w + e.w * __expf(0.5f * l.w);
    *(float4*)(out + idx) = x0;
    *(float4*)(out + 524288 + idx) = m;
    *(float4*)(out + 1048576 + idx) = l;
}

extern "C" void kernel_launch(void* const* d_in, const int* in_sizes, int n_in,
                              void* d_out, int out_size, void* d_ws, size_t ws_size,
                              hipStream_t stream) {
    const float* ctx    = (const float*)d_in[0];
    const int*   sid    = (const int*)  d_in[1];
    const float* eps    = (const float*)d_in[2];
    const float* w1     = (const float*)d_in[3];
    const float* b1     = (const float*)d_in[4];
    const float* w2     = (const float*)d_in[5];
    const float* b2     = (const float*)d_in[6];
    const float* subj_w = (const float*)d_in[7];
    const float* subj_b = (const float*)d_in[8];
    const float* lv_w   = (const float*)d_in[9];
    const float* lv_b   = (const float*)d_in[10];
    float* out = (float*)d_out;

    float* ws   = (float*)d_ws;
    float* pp   = ws + OFF_PP;
    float* h0   = ws + OFF_H0;
    float* p1   = ws + OFF_P1;
    float* g    = ws + OFF_G;
    float* p2   = ws + OFF_P2;
    float* hbuf = ws + OFF_H;
    float* mup  = ws + OFF_MUP;
    float* lvp  = ws + OFF_LVP;

    k_pool<<<dim3(BATCH, 32), 256, 0, stream>>>(ctx, pp);
    k_poolred<<<64, 256, 0, stream>>>(pp, h0);
    k_gemm_mlp<<<dim3(4, 32, 2), 256, 0, stream>>>(h0, w1, p1);
    k_red_gelu<<<64, 256, 0, stream>>>(p1, b1, g);
    k_gemm_mlp<<<dim3(4, 32, 2), 256, 0, stream>>>(g, w2, p2);
    k_red_bias<<<64, 256, 0, stream>>>(p2, b2, hbuf);
    k_mu<<<dim3(8, 8, NSUBJ), 256, 0, stream>>>(hbuf, subj_w, sid, mup);
    k_lv<<<dim3(16, 8, 2), 256, 0, stream>>>(hbuf, lv_w, lvp);
    k_combine<<<512, 256, 0, stream>>>(mup, lvp, eps, subj_b, lv_b, sid, out);
}

// Round 4
// 184.567 us; speedup vs baseline: 2.7022x; 1.2290x over previous
//
#include <hip/hip_runtime.h>
#include <math.h>

#define HID   1024
#define OUTD  8192
#define NSUBJ 8
#define BATCH 64
#define TLEN  512

// ws layout (float offsets)
#define OFF_PP    0u           // pool partials: 16*64*1024 = 1048576
#define OFF_P1    1048576u     // gemm1 partials: 32*64*1024 = 2097152
#define OFF_P2    3145728u     // gemm2 partials: 32*64*1024
#define OFF_H     5242880u     // 64*1024
#define OFF_MUP   5308416u     // mu partials: 8*64*8192 = 4194304
#define OFF_LVP   9502720u     // lv partials: 8*64*8192

// ---------------- mean pool, stage 1: partial sums over 32-t chunks ----------------
__global__ __launch_bounds__(256) void k_pool(const float* __restrict__ ctx,
                                              float* __restrict__ pp) {
    int b  = blockIdx.x;   // 64
    int tc = blockIdx.y;   // 16
    int hid = threadIdx.x * 4;
    const float* base = ctx + ((size_t)b * TLEN + (size_t)tc * 32) * HID + hid;
    float4 acc = make_float4(0.f, 0.f, 0.f, 0.f);
#pragma unroll 8
    for (int t = 0; t < 32; ++t) {
        float4 v = *(const float4*)(base + (size_t)t * HID);
        acc.x += v.x; acc.y += v.y; acc.z += v.z; acc.w += v.w;
    }
    *(float4*)(pp + ((size_t)tc * BATCH + b) * HID + hid) = acc;
}

// -------- MLP layer 1: fused pool-reduce (LDS x-tile) + GEMM partial --------
__global__ __launch_bounds__(256) void k_mlp1(const float* __restrict__ pp,
                                              const float* __restrict__ w1,
                                              float* __restrict__ p1) {
    __shared__ float xs[32][34];
    int j  = blockIdx.x * 256 + threadIdx.x;  // 4 jchunks
    int k0 = blockIdx.y * 32;                 // 32 kchunks
    int b0 = blockIdx.z * 32;                 // 2 bgroups
    {
        int bb = threadIdx.x >> 3;
        int kk = (threadIdx.x & 7) * 4;
        float4 s = make_float4(0.f, 0.f, 0.f, 0.f);
#pragma unroll
        for (int tc = 0; tc < 16; ++tc) {
            float4 v = *(const float4*)(pp + (size_t)tc * 65536 + (b0 + bb) * 1024 + k0 + kk);
            s.x += v.x; s.y += v.y; s.z += v.z; s.w += v.w;
        }
        const float inv = 1.0f / 512.0f;
        xs[bb][kk]     = s.x * inv;
        xs[bb][kk + 1] = s.y * inv;
        xs[bb][kk + 2] = s.z * inv;
        xs[bb][kk + 3] = s.w * inv;
    }
    __syncthreads();
    float acc[32];
#pragma unroll
    for (int i = 0; i < 32; ++i) acc[i] = 0.f;
    for (int kk = 0; kk < 32; kk += 2) {
        float wa = w1[(size_t)(k0 + kk) * HID + j];
        float wb = w1[(size_t)(k0 + kk + 1) * HID + j];
#pragma unroll
        for (int i = 0; i < 32; ++i) {
            acc[i] = fmaf(xs[i][kk], wa, acc[i]);
            acc[i] = fmaf(xs[i][kk + 1], wb, acc[i]);
        }
    }
    float* dst = p1 + (size_t)blockIdx.y * 65536;
#pragma unroll
    for (int i = 0; i < 32; ++i) dst[(b0 + i) * 1024 + j] = acc[i];
}

// -------- MLP layer 2: fused reduce+bias+exact-GELU (LDS x-tile) + GEMM partial ----
__global__ __launch_bounds__(256) void k_mlp2(const float* __restrict__ p1,
                                              const float* __restrict__ b1,
                                              const float* __restrict__ w2,
                                              float* __restrict__ p2) {
    __shared__ float xs[32][34];
    int j  = blockIdx.x * 256 + threadIdx.x;
    int k0 = blockIdx.y * 32;
    int b0 = blockIdx.z * 32;
    {
        int bb = threadIdx.x >> 3;
        int kk = (threadIdx.x & 7) * 4;
        float4 s = make_float4(0.f, 0.f, 0.f, 0.f);
#pragma unroll
        for (int kc = 0; kc < 32; ++kc) {
            float4 v = *(const float4*)(p1 + (size_t)kc * 65536 + (b0 + bb) * 1024 + k0 + kk);
            s.x += v.x; s.y += v.y; s.z += v.z; s.w += v.w;
        }
        float4 bbv = *(const float4*)(b1 + k0 + kk);
        s.x += bbv.x; s.y += bbv.y; s.z += bbv.z; s.w += bbv.w;
        const float r = 0.70710678118654752f;
        xs[bb][kk]     = 0.5f * s.x * (1.0f + erff(s.x * r));
        xs[bb][kk + 1] = 0.5f * s.y * (1.0f + erff(s.y * r));
        xs[bb][kk + 2] = 0.5f * s.z * (1.0f + erff(s.z * r));
        xs[bb][kk + 3] = 0.5f * s.w * (1.0f + erff(s.w * r));
    }
    __syncthreads();
    float acc[32];
#pragma unroll
    for (int i = 0; i < 32; ++i) acc[i] = 0.f;
    for (int kk = 0; kk < 32; kk += 2) {
        float wa = w2[(size_t)(k0 + kk) * HID + j];
        float wb = w2[(size_t)(k0 + kk + 1) * HID + j];
#pragma unroll
        for (int i = 0; i < 32; ++i) {
            acc[i] = fmaf(xs[i][kk], wa, acc[i]);
            acc[i] = fmaf(xs[i][kk + 1], wb, acc[i]);
        }
    }
    float* dst = p2 + (size_t)blockIdx.y * 65536;
#pragma unroll
    for (int i = 0; i < 32; ++i) dst[(b0 + i) * 1024 + j] = acc[i];
}

// ---------------- reduce 32 partials + bias -> hbuf ----------------
__global__ __launch_bounds__(256) void k_red_bias(const float* __restrict__ p,
                                                  const float* __restrict__ bias,
                                                  float* __restrict__ out) {
    int i = (blockIdx.x * 256 + threadIdx.x) * 4;  // 64 blocks
    int j = i & (HID - 1);
    float4 s = make_float4(0.f, 0.f, 0.f, 0.f);
#pragma unroll
    for (int kc = 0; kc < 32; ++kc) {
        float4 v = *(const float4*)(p + (size_t)kc * 65536 + i);
        s.x += v.x; s.y += v.y; s.z += v.z; s.w += v.w;
    }
    float4 bb = *(const float4*)(bias + j);
    s.x += bb.x; s.y += bb.y; s.z += bb.z; s.w += bb.w;
    *(float4*)(out + i) = s;
}

// ---------------- mu tile body: NS samples, single k-pass, wv prefetch ----------------
template <int NS>
__device__ __forceinline__ void mu_tile(const float* __restrict__ hmat,
                                        const float* __restrict__ wbase,
                                        float* __restrict__ mup_kc,
                                        const int* bo, int n, int k0, int o) {
    float4 acc[NS];
#pragma unroll
    for (int i = 0; i < NS; ++i) acc[i] = make_float4(0.f, 0.f, 0.f, 0.f);
    float4 wv[4];
#pragma unroll
    for (int kk = 0; kk < 4; ++kk)
        wv[kk] = *(const float4*)(wbase + (size_t)(k0 + kk) * OUTD + o);
    for (int k = k0; k < k0 + 128; k += 4) {
        float4 hv[NS];
#pragma unroll
        for (int i = 0; i < NS; ++i)
            hv[i] = *(const float4*)(hmat + bo[i] * HID + k);
        int kn = (k + 4 < k0 + 128) ? (k + 4) : k0;  // last-iter reload, harmless
        float4 wn[4];
#pragma unroll
        for (int kk = 0; kk < 4; ++kk)
            wn[kk] = *(const float4*)(wbase + (size_t)(kn + kk) * OUTD + o);
#pragma unroll
        for (int kk = 0; kk < 4; ++kk) {
            float4 w = wv[kk];
#pragma unroll
            for (int i = 0; i < NS; ++i) {
                float h = (kk == 0) ? hv[i].x : (kk == 1) ? hv[i].y
                        : (kk == 2) ? hv[i].z : hv[i].w;
                acc[i].x = fmaf(h, w.x, acc[i].x);
                acc[i].y = fmaf(h, w.y, acc[i].y);
                acc[i].z = fmaf(h, w.z, acc[i].z);
                acc[i].w = fmaf(h, w.w, acc[i].w);
            }
        }
#pragma unroll
        for (int kk = 0; kk < 4; ++kk) wv[kk] = wn[kk];
    }
#pragma unroll
    for (int i = 0; i < NS; ++i)
        if (i < n) *(float4*)(mup_kc + (size_t)bo[i] * OUTD + o) = acc[i];
}

// ------- mu partial: inline ballot grouping, NS-dispatched single-pass tiles -------
__global__ __launch_bounds__(256) void k_mu(const float* __restrict__ hmat,
                                            const float* __restrict__ subj_w,
                                            const int* __restrict__ sid,
                                            float* __restrict__ mup) {
    int o  = blockIdx.x * 1024 + threadIdx.x * 4;  // 8 ochunks
    int k0 = blockIdx.y * 128;                     // 8 kchunks
    int s  = blockIdx.z;                           // 8 subjects
    int lane = threadIdx.x & 63;
    int mysid = sid[lane];
    unsigned long long m = __ballot(mysid == s);
    int ns = __popcll(m);
    if (ns == 0) return;
    const float* wbase = subj_w + (size_t)s * HID * OUTD;
    float* mup_kc = mup + (size_t)blockIdx.y * BATCH * OUTD;
    unsigned long long mm = m;
    for (int base = 0; base < ns; base += 12) {
        int take = ns - base; if (take > 12) take = 12;
        int fb = (int)__builtin_ctzll(mm);
        int bo[12];
#pragma unroll
        for (int i = 0; i < 12; ++i) {
            bo[i] = (mm != 0ull) ? (int)__builtin_ctzll(mm) : fb;
            if (mm != 0ull) mm &= (mm - 1ull);
        }
        if (take <= 4)       mu_tile<4>(hmat, wbase, mup_kc, bo, take, k0, o);
        else if (take <= 8)  mu_tile<8>(hmat, wbase, mup_kc, bo, take, k0, o);
        else                 mu_tile<12>(hmat, wbase, mup_kc, bo, take, k0, o);
    }
}

// ---------------- log_var partial: 2 bgroups of 32, wv prefetch ----------------
__global__ __launch_bounds__(256) void k_lv(const float* __restrict__ hmat,
                                            const float* __restrict__ lv_w,
                                            float* __restrict__ lvp) {
    int o  = blockIdx.x * 512 + threadIdx.x * 2;  // 16 ochunks
    int k0 = blockIdx.y * 128;                    // 8 kchunks
    int b0 = blockIdx.z * 32;                     // 2 bgroups
    float2 acc[32];
#pragma unroll
    for (int i = 0; i < 32; ++i) acc[i] = make_float2(0.f, 0.f);
    float2 wv0 = *(const float2*)(lv_w + (size_t)k0 * OUTD + o);
    float2 wv1 = *(const float2*)(lv_w + (size_t)(k0 + 1) * OUTD + o);
    for (int k = k0; k < k0 + 128; k += 2) {
        float2 hv[32];
#pragma unroll
        for (int i = 0; i < 32; ++i)
            hv[i] = *(const float2*)(hmat + (b0 + i) * HID + k);
        int kn = (k + 2 < k0 + 128) ? (k + 2) : k0;
        float2 wn0 = *(const float2*)(lv_w + (size_t)kn * OUTD + o);
        float2 wn1 = *(const float2*)(lv_w + (size_t)(kn + 1) * OUTD + o);
#pragma unroll
        for (int i = 0; i < 32; ++i) {
            acc[i].x = fmaf(hv[i].x, wv0.x, acc[i].x);
            acc[i].y = fmaf(hv[i].x, wv0.y, acc[i].y);
            acc[i].x = fmaf(hv[i].y, wv1.x, acc[i].x);
            acc[i].y = fmaf(hv[i].y, wv1.y, acc[i].y);
        }
        wv0 = wn0; wv1 = wn1;
    }
#pragma unroll
    for (int i = 0; i < 32; ++i) {
        float* dst = lvp + ((size_t)blockIdx.y * BATCH + b0 + i) * OUTD + o;
        dst[0] = acc[i].x; dst[1] = acc[i].y;
    }
}

// ---------------- combine: biases, clip, sample; write x0|mu|log_var ----------------
__global__ __launch_bounds__(256) void k_combine(const float* __restrict__ mup,
                                                 const float* __restrict__ lvp,
                                                 const float* __restrict__ eps,
                                                 const float* __restrict__ subj_b,
                                                 const float* __restrict__ lv_b,
                                                 const int* __restrict__ sid,
                                                 float* __restrict__ out) {
    int idx = (blockIdx.x * 256 + threadIdx.x) * 4;  // over 524288
    int b = idx >> 13;
    int o = idx & (OUTD - 1);
    float4 m = make_float4(0.f, 0.f, 0.f, 0.f);
    float4 l = make_float4(0.f, 0.f, 0.f, 0.f);
#pragma unroll
    for (int kc = 0; kc < 8; ++kc) {
        float4 t = *(const float4*)(mup + (size_t)kc * 524288 + idx);
        m.x += t.x; m.y += t.y; m.z += t.z; m.w += t.w;
        float4 u = *(const float4*)(lvp + (size_t)kc * 524288 + idx);
        l.x += u.x; l.y += u.y; l.z += u.z; l.w += u.w;
    }
    int s = sid[b];
    float4 sb = *(const float4*)(subj_b + s * OUTD + o);
    float4 lb = *(const float4*)(lv_b + o);
    m.x += sb.x; m.y += sb.y; m.z += sb.z; m.w += sb.w;
    l.x = fminf(fmaxf(l.x + lb.x, -10.f), 2.f);
    l.y = fminf(fmaxf(l.y + lb.y, -10.f), 2.f);
    l.z = fminf(fmaxf(l.z + lb.z, -10.f), 2.f);
    l.w = fminf(fmaxf(l.w + lb.w, -10.f), 2.f);
    float4 e = *(const float4*)(eps + idx);
    float4 x0;
    x0.x = m.x + e.x * __expf(0.5f * l.x);
    x0.y = m.y + e.y * __expf(0.5f * l.y);
    x0.z = m.z + e.z * __expf(0.5f * l.z);
    x0.w = m.w + e.w * __expf(0.5f * l.w);
    *(float4*)(out + idx) = x0;
    *(float4*)(out + 524288 + idx) = m;
    *(float4*)(out + 1048576 + idx) = l;
}

extern "C" void kernel_launch(void* const* d_in, const int* in_sizes, int n_in,
                              void* d_out, int out_size, void* d_ws, size_t ws_size,
                              hipStream_t stream) {
    const float* ctx    = (const float*)d_in[0];
    const int*   sid    = (const int*)  d_in[1];
    const float* eps    = (const float*)d_in[2];
    const float* w1     = (const float*)d_in[3];
    const float* b1     = (const float*)d_in[4];
    const float* w2     = (const float*)d_in[5];
    const float* b2     = (const float*)d_in[6];
    const float* subj_w = (const float*)d_in[7];
    const float* subj_b = (const float*)d_in[8];
    const float* lv_w   = (const float*)d_in[9];
    const float* lv_b   = (const float*)d_in[10];
    float* out = (float*)d_out;

    float* ws   = (float*)d_ws;
    float* pp   = ws + OFF_PP;
    float* p1   = ws + OFF_P1;
    float* p2   = ws + OFF_P2;
    float* hbuf = ws + OFF_H;
    float* mup  = ws + OFF_MUP;
    float* lvp  = ws + OFF_LVP;

    k_pool<<<dim3(BATCH, 16), 256, 0, stream>>>(ctx, pp);
    k_mlp1<<<dim3(4, 32, 2), 256, 0, stream>>>(pp, w1, p1);
    k_mlp2<<<dim3(4, 32, 2), 256, 0, stream>>>(p1, b1, w2, p2);
    k_red_bias<<<64, 256, 0, stream>>>(p2, b2, hbuf);
    k_mu<<<dim3(8, 8, NSUBJ), 256, 0, stream>>>(hbuf, subj_w, sid, mup);
    k_lv<<<dim3(16, 8, 2), 256, 0, stream>>>(hbuf, lv_w, lvp);
    k_combine<<<512, 256, 0, stream>>>(mup, lvp, eps, subj_b, lv_b, sid, out);
}